// Round 1
// baseline (749.390 us; speedup 1.0000x reference)
//
#include <hip/hip_runtime.h>
#include <hip/hip_bf16.h>

// Problem constants (reference: R=8, N=4096, IN_F=OUT_F=64)
#define RR 8
#define NN 4096
#define FF 64

typedef float f32x4 __attribute__((ext_vector_type(4)));
typedef short bf16x8 __attribute__((ext_vector_type(8)));

__device__ __forceinline__ short f2b(float f) {
  __hip_bfloat16 h = __float2bfloat16(f);
  return __builtin_bit_cast(short, h);
}

__device__ __forceinline__ bf16x8 cvt8(f32x4 lo, f32x4 hi) {
  bf16x8 r;
  r[0] = f2b(lo[0]); r[1] = f2b(lo[1]); r[2] = f2b(lo[2]); r[3] = f2b(lo[3]);
  r[4] = f2b(hi[0]); r[5] = f2b(hi[1]); r[6] = f2b(hi[2]); r[7] = f2b(hi[3]);
  return r;
}

// ---------------------------------------------------------------------------
// Kernel 0: zero the output (harness poisons d_out with 0xAA before every
// timed launch; main kernel accumulates with atomics).
__global__ __launch_bounds__(256) void zero_out(float4* __restrict__ out) {
  out[blockIdx.x * 256 + threadIdx.x] = make_float4(0.f, 0.f, 0.f, 0.f);
}

// ---------------------------------------------------------------------------
// Kernel 1: Zt[r][o][m] = sum_i W[r][o][i] * x[m][i], stored bf16 in d_ws.
// Layout: Zt[r*64*4096 + o*4096 + m]. MFMA: A = W[r] (o x i), B = x^T (i x m).
// grid = (64 m-tiles, 8 r), block = 256 (4 waves, each wave 16 m-cols).
__global__ __launch_bounds__(256) void compute_zt(const float* __restrict__ x,
                                                  const float* __restrict__ w,
                                                  short* __restrict__ zt) {
  const int tid   = threadIdx.x;
  const int lane  = tid & 63;
  const int wv    = tid >> 6;
  const int row16 = lane & 15;
  const int quad  = lane >> 4;
  const int r     = blockIdx.y;
  const int m0    = blockIdx.x * 64 + wv * 16;   // this wave's 16 m columns

  // B fragments: B[k=i][col=m] = x[m][i]; lane holds 8 consecutive i of row m.
  bf16x8 bfr[2];
#pragma unroll
  for (int s = 0; s < 2; ++s) {
    const float* p = x + (size_t)(m0 + row16) * FF + s * 32 + quad * 8;
    bfr[s] = cvt8(*(const f32x4*)p, *(const f32x4*)(p + 4));
  }

  f32x4 acc[4] = {{0.f,0.f,0.f,0.f},{0.f,0.f,0.f,0.f},
                  {0.f,0.f,0.f,0.f},{0.f,0.f,0.f,0.f}};
#pragma unroll
  for (int og = 0; og < 4; ++og) {
#pragma unroll
    for (int s = 0; s < 2; ++s) {
      const float* p = w + ((size_t)r * FF + og * 16 + row16) * FF + s * 32 + quad * 8;
      bf16x8 afr = cvt8(*(const f32x4*)p, *(const f32x4*)(p + 4));
      acc[og] = __builtin_amdgcn_mfma_f32_16x16x32_bf16(afr, bfr[s], acc[og], 0, 0, 0);
    }
  }

  // C/D layout: col = lane&15 (m), row = quad*4 + reg (o).
#pragma unroll
  for (int og = 0; og < 4; ++og)
#pragma unroll
    for (int j = 0; j < 4; ++j) {
      int o = og * 16 + quad * 4 + j;
      int m = m0 + row16;
      zt[((size_t)r * FF + o) * NN + m] = f2b(acc[og][j]);
    }
}

// ---------------------------------------------------------------------------
// Kernel 2: y[n][o] += sum_{m in ksplit} A[r][n][m] * Zt[r][o][m]
// grid = (64 row-tiles, 16 = r*2 + khalf), block = 256 (4 waves x 16 rows).
// A: direct global->reg fp32 loads (2x dwordx4/lane, 128B/row fully used),
// cvt to bf16. B: 16B contiguous bf16 loads from Zt (L1/L2 resident).
// No LDS, no barriers; one-chunk (BK=64) register prefetch.

struct Chunk {
  f32x4  alo[2], ahi[2];
  bf16x8 b[2][4];
};

__device__ __forceinline__ Chunk load_chunk(const float* __restrict__ aptr,
                                            const short* __restrict__ zbase,
                                            int row16, int k0) {
  Chunk c;
#pragma unroll
  for (int s = 0; s < 2; ++s) {
    const float* p = aptr + k0 + s * 32;
    c.alo[s] = *(const f32x4*)p;
    c.ahi[s] = *(const f32x4*)(p + 4);
#pragma unroll
    for (int cg = 0; cg < 4; ++cg) {
      c.b[s][cg] = *(const bf16x8*)(zbase + (size_t)(cg * 16 + row16) * NN + k0 + s * 32);
    }
  }
  return c;
}

__global__ __launch_bounds__(256) void rgcn_main(const float* __restrict__ adj,
                                                 const short* __restrict__ zt,
                                                 float* __restrict__ out) {
  const int tid   = threadIdx.x;
  const int lane  = tid & 63;
  const int wv    = tid >> 6;
  const int row16 = lane & 15;
  const int quad  = lane >> 4;

  const int nt    = blockIdx.x;        // row tile: 64 rows
  const int rk    = blockIdx.y;        // r*2 + khalf
  const int r     = rk >> 1;
  const int half  = rk & 1;
  const int n0    = nt * 64;
  const int row   = n0 + wv * 16 + row16;

  // Per-lane base pointers. Lane holds A[row][k0 + quad*8 .. +7].
  const float* aptr  = adj + (size_t)r * NN * NN + (size_t)row * NN
                           + half * 2048 + quad * 8;
  const short* zbase = zt + (size_t)r * FF * NN + half * 2048 + quad * 8;

  f32x4 acc[4] = {{0.f,0.f,0.f,0.f},{0.f,0.f,0.f,0.f},
                  {0.f,0.f,0.f,0.f},{0.f,0.f,0.f,0.f}};

  Chunk cur = load_chunk(aptr, zbase, row16, 0);

  for (int k0 = 0; k0 < 2048; k0 += 64) {
    // Prefetch next chunk (wraps to 0 on last iter: valid memory, unused).
    int kn = (k0 + 64 < 2048) ? (k0 + 64) : 0;
    Chunk nxt = load_chunk(aptr, zbase, row16, kn);

#pragma unroll
    for (int s = 0; s < 2; ++s) {
      bf16x8 afr = cvt8(cur.alo[s], cur.ahi[s]);
#pragma unroll
      for (int cg = 0; cg < 4; ++cg)
        acc[cg] = __builtin_amdgcn_mfma_f32_16x16x32_bf16(afr, cur.b[s][cg], acc[cg], 0, 0, 0);
    }
    cur = nxt;
  }

  // Epilogue: C/D layout col = lane&15 (o within group), row = quad*4 + reg.
#pragma unroll
  for (int cg = 0; cg < 4; ++cg)
#pragma unroll
    for (int j = 0; j < 4; ++j) {
      int orow = n0 + wv * 16 + quad * 4 + j;
      int ocol = cg * 16 + row16;
      atomicAdd(out + (size_t)orow * FF + ocol, acc[cg][j]);
    }
}

// ---------------------------------------------------------------------------
extern "C" void kernel_launch(void* const* d_in, const int* in_sizes, int n_in,
                              void* d_out, int out_size, void* d_ws, size_t ws_size,
                              hipStream_t stream) {
  const float* adj = (const float*)d_in[0];   // [8, 4096, 4096] fp32
  const float* x   = (const float*)d_in[1];   // [4096, 64] fp32
  const float* w   = (const float*)d_in[2];   // [8, 64, 64] fp32
  float* out = (float*)d_out;                 // [4096, 64] fp32
  short* zt  = (short*)d_ws;                  // [8, 64, 4096] bf16 = 4 MiB

  zero_out<<<dim3(NN * FF / (4 * 256)), 256, 0, stream>>>((float4*)out);
  compute_zt<<<dim3(NN / 64, RR), 256, 0, stream>>>(x, w, zt);
  rgcn_main<<<dim3(NN / 64, RR * 2), 256, 0, stream>>>(adj, zt, out);
}